// Round 12
// baseline (536.394 us; speedup 1.0000x reference)
//
#include <hip/hip_runtime.h>
#include <hip/hip_fp16.h>
#include <hip/hip_fp8.h>

#define F_IN 61
#define H 32
#define BUCK_BITS 8                  // 256 nodes per bucket
#define BUCK_SZ   256
#define CHUNK     8192               // edges per block in hist/bin passes

typedef __hip_fp8_storage_t fp8_t;   // unsigned char

// ---------- generic 3-level exclusive scan (for the counts array) ----------
__global__ __launch_bounds__(256) void scan1_kernel(const int* __restrict__ in,
                                                    int* __restrict__ scanned,
                                                    int* __restrict__ btot, int n) {
    __shared__ int s[256];
    int tid = threadIdx.x;
    int i = blockIdx.x * 256 + tid;
    int v = (i < n) ? in[i] : 0;
    s[tid] = v;
    __syncthreads();
    for (int off = 1; off < 256; off <<= 1) {
        int t = (tid >= off) ? s[tid - off] : 0;
        __syncthreads();
        s[tid] += t;
        __syncthreads();
    }
    if (i < n) scanned[i] = s[tid] - v;
    if (tid == 255) btot[blockIdx.x] = s[255];
}

__global__ __launch_bounds__(1024) void scan2_kernel(int* __restrict__ btot, int nB) {
    __shared__ int s[1024];
    int tid = threadIdx.x;
    int v = (tid < nB) ? btot[tid] : 0;
    s[tid] = v;
    __syncthreads();
    for (int off = 1; off < 1024; off <<= 1) {
        int t = (tid >= off) ? s[tid - off] : 0;
        __syncthreads();
        s[tid] += t;
        __syncthreads();
    }
    if (tid < nB) btot[tid] = s[tid] - v;
}

__global__ __launch_bounds__(256) void scan3b_kernel(const int* __restrict__ scanned,
                                                     const int* __restrict__ btot,
                                                     int* __restrict__ outv, int n) {
    int i = blockIdx.x * 256 + threadIdx.x;
    if (i < n) outv[i] = scanned[i] + btot[blockIdx.x];
}

// ---------- pass A: per-(block,bucket) histogram ----------
__global__ __launch_bounds__(256) void histA_kernel(const int* __restrict__ ei,
                                                    int* __restrict__ counts,
                                                    int E, int B, int nbuck) {
    __shared__ int h[640];
    int tid = threadIdx.x;
    for (int i = tid; i < nbuck; i += 256) h[i] = 0;
    __syncthreads();
    int e0 = blockIdx.x * CHUNK;
    int e1 = e0 + CHUNK; if (e1 > E) e1 = E;
    for (int e = e0 + tid; e < e1; e += 256)
        atomicAdd(&h[ei[E + e] >> BUCK_BITS], 1);
    __syncthreads();
    for (int i = tid; i < nbuck; i += 256) counts[i * B + blockIdx.x] = h[i];
}

// ---------- pass B: bin edges into per-(block,bucket) EXCLUSIVE ranges ----------
// pack = (src<<8)|(dst&255); src < 2^18 fits.
__global__ __launch_bounds__(256) void binB_kernel(const int* __restrict__ ei,
                                                   const int* __restrict__ counts,
                                                   int* __restrict__ tmp,
                                                   int E, int B, int nbuck) {
    __shared__ int lcur[640];
    int tid = threadIdx.x;
    for (int i = tid; i < nbuck; i += 256) lcur[i] = counts[i * B + blockIdx.x];
    __syncthreads();
    int e0 = blockIdx.x * CHUNK;
    int e1 = e0 + CHUNK; if (e1 > E) e1 = E;
    for (int e = e0 + tid; e < e1; e += 256) {
        int s = ei[e];
        int d = ei[E + e];
        int pos = atomicAdd(&lcur[d >> BUCK_BITS], 1);
        tmp[pos] = (s << BUCK_BITS) | (d & (BUCK_SZ - 1));
    }
}

// ---------- pass C: per-bucket degree + row_start + dinv + final CSR scatter ----------
// src_sorted stores BYTE offsets (src*32) for the fp8 row table.
__global__ __launch_bounds__(256) void binC_kernel(const int* __restrict__ counts,
                                                   const int* __restrict__ tmp,
                                                   int* __restrict__ src_sorted,
                                                   int* __restrict__ row_start,
                                                   float* __restrict__ dinv,
                                                   int N, int E, int B, int nbuck) {
    __shared__ int hist[BUCK_SZ];
    __shared__ int pre[BUCK_SZ];
    __shared__ int lcur[BUCK_SZ];
    int tid = threadIdx.x;
    int b = blockIdx.x;
    int base = b << BUCK_BITS;
    int e0 = counts[b * B];
    int e1 = (b + 1 < nbuck) ? counts[(b + 1) * B] : E;
    hist[tid] = 0;
    __syncthreads();
    for (int e = e0 + tid; e < e1; e += 256)
        atomicAdd(&hist[tmp[e] & (BUCK_SZ - 1)], 1);
    __syncthreads();
    int v = hist[tid];
    pre[tid] = v;
    __syncthreads();
    for (int off = 1; off < 256; off <<= 1) {
        int t = (tid >= off) ? pre[tid - off] : 0;
        __syncthreads();
        pre[tid] += t;
        __syncthreads();
    }
    int excl = pre[tid] - v;
    int node = base + tid;
    if (node < N) {
        row_start[node] = e0 + excl;
        dinv[node] = rsqrtf((float)v + 1.0f);     // +1 self-loop
        if (node == N - 1) row_start[N] = E;
    }
    lcur[tid] = e0 + excl;
    __syncthreads();
    for (int e = e0 + tid; e < e1; e += 256) {
        int p = tmp[e];
        int pos = atomicAdd(&lcur[p & (BUCK_SZ - 1)], 1);
        src_sorted[pos] = (p >> BUCK_BITS) << 5;   // byte offset of fp8 row
    }
}

// ---------- layer 1 dense: hs1 = fp8( dinv * (x @ W1) ) ----------
__global__ __launch_bounds__(256) void gemm1_kernel(const float* __restrict__ x,
                                                    const float* __restrict__ W,
                                                    const float* __restrict__ dinv,
                                                    fp8_t* __restrict__ h, int N) {
    __shared__ float Ws[F_IN * H];
    __shared__ float xs[8 * F_IN];
    int tid = threadIdx.x;
    for (int i = tid; i < F_IN * H; i += 256) Ws[i] = W[i];
    int nb = blockIdx.x * 8;
    int navail = N - nb; if (navail > 8) navail = 8;
    const float* xb = x + (long long)nb * F_IN;
    for (int i = tid; i < navail * F_IN; i += 256) xs[i] = xb[i];
    __syncthreads();
    int nl = tid >> 5, f = tid & 31;
    int node = nb + nl;
    if (node < N) {
        float s = 0.f;
        #pragma unroll
        for (int k = 0; k < F_IN; k++) s += xs[nl * F_IN + k] * Ws[k * H + f];
        h[((long long)node << 5) + f] =
            __hip_cvt_float_to_fp8(s * dinv[node], __HIP_SATFINITE, __HIP_E4M3);
    }
}

// ---------- fused agg + GEMM (fp8 gathers: 32B rows, L2-resident table) ----------
// Lane map per node (32 lanes): p = lane>>4 (edge parity), fp = lane&15
// (feature pair). Each lane gathers 2 fp8 values {2fp,2fp+1} of edge j+2k+p.
// Invalid slots gather the dedicated ZERO ROW at byte offset N*32.
__global__ __launch_bounds__(256) void agg_gemm_kernel(const int* __restrict__ row_start,
                                                       const int* __restrict__ src_sorted,
                                                       const float* __restrict__ dinv,
                                                       const fp8_t* __restrict__ hs,
                                                       const float* __restrict__ b,
                                                       const float* __restrict__ Wn,
                                                       fp8_t* __restrict__ hout, int N) {
    __shared__ float Ws[H * H];
    __shared__ float t[8 * H];
    int tid = threadIdx.x;
    for (int i = tid; i < H * H; i += 256) Ws[i] = Wn[i];
    int nl = tid >> 5;
    int lane32 = tid & 31;
    int p = lane32 >> 4;
    int fp = lane32 & 15;
    int node = blockIdx.x * 8 + nl;
    int zoff = N << 5;
    float2 acc = make_float2(0.f, 0.f);
    if (node < N) {
        const char* hbase = (const char*)hs + (fp << 1);
        int e0 = row_start[node], e1 = row_start[node + 1];
        int idxv = (e0 + lane32 < e1) ? src_sorted[e0 + lane32] : zoff;
        for (int base = e0; base < e1; base += 32) {
            int w = e1 - base; if (w > 32) w = 32;
            int idxN = (base + 32 + lane32 < e1) ? src_sorted[base + 32 + lane32] : zoff;
            for (int j = 0; j < w; j += 16) {
                int offs[8];
                #pragma unroll
                for (int k = 0; k < 8; k++) offs[k] = __shfl(idxv, j + 2 * k + p, 32);
                unsigned short g[8];
                #pragma unroll
                for (int k = 0; k < 8; k++) g[k] = *(const unsigned short*)(hbase + offs[k]);
                #pragma unroll
                for (int k = 0; k < 8; k++) {
                    __half2_raw hr = __hip_cvt_fp8x2_to_halfraw2(g[k], __HIP_E4M3);
                    float2 fv = __half22float2(*(__half2*)&hr);
                    acc.x += fv.x; acc.y += fv.y;
                }
            }
            idxv = idxN;
        }
    }
    acc.x += __shfl_xor(acc.x, 16, 32);
    acc.y += __shfl_xor(acc.y, 16, 32);
    if (node < N && p == 0) {
        float di = dinv[node];
        unsigned short sr = *(const unsigned short*)((const char*)hs +
                          ((long long)node << 5) + (fp << 1));
        __half2_raw hr = __hip_cvt_fp8x2_to_halfraw2(sr, __HIP_E4M3);
        float2 s2 = __half22float2(*(__half2*)&hr);
        float2 bv = ((const float2*)b)[fp];
        float rx = fmaxf(di * (acc.x + s2.x) + bv.x, 0.f);
        float ry = fmaxf(di * (acc.y + s2.y) + bv.y, 0.f);
        ((float2*)&t[nl * H])[fp] = make_float2(rx, ry);
    }
    __syncthreads();
    if (node < N) {
        int f = lane32;
        float s = 0.f;
        #pragma unroll
        for (int k = 0; k < H; k++) s += t[nl * H + k] * Ws[k * H + f];
        hout[((long long)node << 5) + f] =
            __hip_cvt_float_to_fp8(s * dinv[node], __HIP_SATFINITE, __HIP_E4M3);
    }
}

// ---------- final layer: X5 = relu(...), pool into 64 spread copies ----------
__global__ __launch_bounds__(256) void agg_pool_kernel(const int* __restrict__ row_start,
                                                       const int* __restrict__ src_sorted,
                                                       const float* __restrict__ dinv,
                                                       const fp8_t* __restrict__ hs,
                                                       const float* __restrict__ b,
                                                       float* __restrict__ gs, int N) {
    __shared__ float t[8 * H];
    int tid = threadIdx.x;
    int nl = tid >> 5;
    int lane32 = tid & 31;
    int p = lane32 >> 4;
    int fp = lane32 & 15;
    int node = blockIdx.x * 8 + nl;
    int zoff = N << 5;
    float2 acc = make_float2(0.f, 0.f);
    if (node < N) {
        const char* hbase = (const char*)hs + (fp << 1);
        int e0 = row_start[node], e1 = row_start[node + 1];
        int idxv = (e0 + lane32 < e1) ? src_sorted[e0 + lane32] : zoff;
        for (int base = e0; base < e1; base += 32) {
            int w = e1 - base; if (w > 32) w = 32;
            int idxN = (base + 32 + lane32 < e1) ? src_sorted[base + 32 + lane32] : zoff;
            for (int j = 0; j < w; j += 16) {
                int offs[8];
                #pragma unroll
                for (int k = 0; k < 8; k++) offs[k] = __shfl(idxv, j + 2 * k + p, 32);
                unsigned short g[8];
                #pragma unroll
                for (int k = 0; k < 8; k++) g[k] = *(const unsigned short*)(hbase + offs[k]);
                #pragma unroll
                for (int k = 0; k < 8; k++) {
                    __half2_raw hr = __hip_cvt_fp8x2_to_halfraw2(g[k], __HIP_E4M3);
                    float2 fv = __half22float2(*(__half2*)&hr);
                    acc.x += fv.x; acc.y += fv.y;
                }
            }
            idxv = idxN;
        }
    }
    acc.x += __shfl_xor(acc.x, 16, 32);
    acc.y += __shfl_xor(acc.y, 16, 32);
    float2 r = make_float2(0.f, 0.f);
    if (node < N && p == 0) {
        float di = dinv[node];
        unsigned short sr = *(const unsigned short*)((const char*)hs +
                          ((long long)node << 5) + (fp << 1));
        __half2_raw hr = __hip_cvt_fp8x2_to_halfraw2(sr, __HIP_E4M3);
        float2 s2 = __half22float2(*(__half2*)&hr);
        float2 bv = ((const float2*)b)[fp];
        r.x = fmaxf(di * (acc.x + s2.x) + bv.x, 0.f);
        r.y = fmaxf(di * (acc.y + s2.y) + bv.y, 0.f);
    }
    if (p == 0) ((float2*)&t[nl * H])[fp] = r;
    __syncthreads();
    if (tid < H) {
        float s = 0.f;
        #pragma unroll
        for (int rI = 0; rI < 8; rI++) s += t[rI * H + tid];
        atomicAdd(&gs[(blockIdx.x & 63) * H + tid], s);
    }
}

// ---------- head ----------
__global__ __launch_bounds__(64) void head_kernel(const float* __restrict__ gs,
                                                  const float* __restrict__ Wl1,
                                                  const float* __restrict__ bl1,
                                                  const float* __restrict__ Wl2,
                                                  const float* __restrict__ bl2,
                                                  float* __restrict__ out) {
    __shared__ float gg[H];
    __shared__ float t[16];
    int tid = threadIdx.x;
    if (tid < H) {
        float s = 0.f;
        for (int c = 0; c < 64; c++) s += gs[c * H + tid];
        gg[tid] = s;
    }
    __syncthreads();
    if (tid < 16) {
        float s = bl1[tid];
        #pragma unroll
        for (int k = 0; k < 32; k++) s += gg[k] * Wl1[k * 16 + tid];
        t[tid] = fmaxf(s, 0.f);
    }
    __syncthreads();
    if (tid < 3) {
        float s = bl2[tid];
        #pragma unroll
        for (int k = 0; k < 16; k++) s += t[k] * Wl2[k * 3 + tid];
        out[tid] = s;
    }
}

extern "C" void kernel_launch(void* const* d_in, const int* in_sizes, int n_in,
                              void* d_out, int out_size, void* d_ws, size_t ws_size,
                              hipStream_t stream) {
    const float* x   = (const float*)d_in[0];
    const int*   ei  = (const int*)d_in[1];
    const float* W1  = (const float*)d_in[2];
    const float* b1  = (const float*)d_in[3];
    const float* W2  = (const float*)d_in[4];
    const float* b2  = (const float*)d_in[5];
    const float* W3  = (const float*)d_in[6];
    const float* b3  = (const float*)d_in[7];
    const float* W4  = (const float*)d_in[8];
    const float* b4  = (const float*)d_in[9];
    const float* Wl1 = (const float*)d_in[10];
    const float* bl1 = (const float*)d_in[11];
    const float* Wl2 = (const float*)d_in[12];
    const float* bl2 = (const float*)d_in[13];
    float* out = (float*)d_out;

    const int N = in_sizes[0] / F_IN;
    const int E = in_sizes[1] / 2;
    const int nbuck = (N + BUCK_SZ - 1) >> BUCK_BITS;      // 586 for N=150000
    const int B = (E + CHUNK - 1) / CHUNK;                 // 293 for E=2.4M
    const int nC = nbuck * B;

    char* ws = (char*)d_ws;
    size_t off = 0;
    auto alloc = [&](size_t bytes) {
        char* p = ws + off;
        off += (bytes + 255) & ~(size_t)255;
        return p;
    };
    float* dinv       = (float*)alloc((size_t)N * 4);
    int*   row_start  = (int*)alloc((size_t)(N + 1) * 4);
    int*   counts     = (int*)alloc((size_t)nC * 4);
    int*   countsS    = (int*)alloc((size_t)nC * 4);
    int*   btot2      = (int*)alloc(((size_t)nC / 256 + 2) * 4);
    int*   src_sorted = (int*)alloc((size_t)E * 4);
    size_t bufBytes   = (size_t)(N + 1) * H;               // fp8 rows + zero row
    size_t tmpBytes   = (size_t)E * 4;
    fp8_t* bufA       = (fp8_t*)alloc(bufBytes > tmpBytes ? bufBytes : tmpBytes);
    fp8_t* bufB       = (fp8_t*)alloc(bufBytes);
    float* gs         = (float*)alloc(64 * H * 4);
    int*   tmp        = (int*)bufA;    // pass-B scratch; dead after binC

    const int TB = 256;
    const int gC  = (nC + TB - 1) / TB;
    const int gN8 = (N + 7) / 8;

    // ---- CSR build (no global atomics anywhere) ----
    hipMemsetAsync(gs, 0, 64 * H * 4, stream);
    histA_kernel<<<B, TB, 0, stream>>>(ei, counts, E, B, nbuck);
    scan1_kernel<<<gC, TB, 0, stream>>>(counts, countsS, btot2, nC);
    scan2_kernel<<<1, 1024, 0, stream>>>(btot2, gC);
    scan3b_kernel<<<gC, TB, 0, stream>>>(countsS, btot2, counts, nC);
    binB_kernel<<<B, TB, 0, stream>>>(ei, counts, tmp, E, B, nbuck);
    binC_kernel<<<nbuck, TB, 0, stream>>>(counts, tmp, src_sorted, row_start, dinv,
                                          N, E, B, nbuck);
    // zero rows (index N) for the padded gathers; after binC (bufA aliased tmp)
    hipMemsetAsync(bufA + (size_t)N * H, 0, H, stream);
    hipMemsetAsync(bufB + (size_t)N * H, 0, H, stream);

    // ---- layers ----
    gemm1_kernel<<<gN8, TB, 0, stream>>>(x, W1, dinv, bufA, N);                                  // hs1
    agg_gemm_kernel<<<gN8, TB, 0, stream>>>(row_start, src_sorted, dinv, bufA, b1, W2, bufB, N); // hs2
    agg_gemm_kernel<<<gN8, TB, 0, stream>>>(row_start, src_sorted, dinv, bufB, b2, W3, bufA, N); // hs3
    agg_gemm_kernel<<<gN8, TB, 0, stream>>>(row_start, src_sorted, dinv, bufA, b3, W4, bufB, N); // hs4
    agg_pool_kernel<<<gN8, TB, 0, stream>>>(row_start, src_sorted, dinv, bufB, b4, gs, N);       // pool(X5)

    head_kernel<<<1, 64, 0, stream>>>(gs, Wl1, bl1, Wl2, bl2, out);
}

// Round 13
// 415.192 us; speedup vs baseline: 1.2919x; 1.2919x over previous
//
#include <hip/hip_runtime.h>
#include <hip/hip_fp16.h>

#define F_IN 61
#define H 32
#define BUCK_BITS 8                  // 256 nodes per bucket
#define BUCK_SZ   256
#define CHUNK     16384              // edges per block in hist/bin passes

// ---------- generic 3-level exclusive scan (for the counts array) ----------
__global__ __launch_bounds__(256) void scan1_kernel(const int* __restrict__ in,
                                                    int* __restrict__ scanned,
                                                    int* __restrict__ btot, int n) {
    __shared__ int s[256];
    int tid = threadIdx.x;
    int i = blockIdx.x * 256 + tid;
    int v = (i < n) ? in[i] : 0;
    s[tid] = v;
    __syncthreads();
    for (int off = 1; off < 256; off <<= 1) {
        int t = (tid >= off) ? s[tid - off] : 0;
        __syncthreads();
        s[tid] += t;
        __syncthreads();
    }
    if (i < n) scanned[i] = s[tid] - v;
    if (tid == 255) btot[blockIdx.x] = s[255];
}

__global__ __launch_bounds__(1024) void scan2_kernel(int* __restrict__ btot, int nB) {
    __shared__ int s[1024];
    int tid = threadIdx.x;
    int v = (tid < nB) ? btot[tid] : 0;
    s[tid] = v;
    __syncthreads();
    for (int off = 1; off < 1024; off <<= 1) {
        int t = (tid >= off) ? s[tid - off] : 0;
        __syncthreads();
        s[tid] += t;
        __syncthreads();
    }
    if (tid < nB) btot[tid] = s[tid] - v;
}

__global__ __launch_bounds__(256) void scan3b_kernel(const int* __restrict__ scanned,
                                                     const int* __restrict__ btot,
                                                     int* __restrict__ outv, int n) {
    int i = blockIdx.x * 256 + threadIdx.x;
    if (i < n) outv[i] = scanned[i] + btot[blockIdx.x];
}

// ---------- pass A: per-(block,bucket) histogram ----------
__global__ __launch_bounds__(256) void histA_kernel(const int* __restrict__ ei,
                                                    int* __restrict__ counts,
                                                    int E, int B, int nbuck) {
    __shared__ int h[640];
    int tid = threadIdx.x;
    for (int i = tid; i < nbuck; i += 256) h[i] = 0;
    __syncthreads();
    int e0 = blockIdx.x * CHUNK;
    int e1 = e0 + CHUNK; if (e1 > E) e1 = E;
    for (int e = e0 + tid; e < e1; e += 256)
        atomicAdd(&h[ei[E + e] >> BUCK_BITS], 1);
    __syncthreads();
    for (int i = tid; i < nbuck; i += 256) counts[i * B + blockIdx.x] = h[i];
}

// ---------- pass B: bin edges into per-(block,bucket) EXCLUSIVE ranges ----------
// pack = (src<<8)|(dst&255); src < 2^18 fits.
__global__ __launch_bounds__(256) void binB_kernel(const int* __restrict__ ei,
                                                   const int* __restrict__ counts,
                                                   int* __restrict__ tmp,
                                                   int E, int B, int nbuck) {
    __shared__ int lcur[640];
    int tid = threadIdx.x;
    for (int i = tid; i < nbuck; i += 256) lcur[i] = counts[i * B + blockIdx.x];
    __syncthreads();
    int e0 = blockIdx.x * CHUNK;
    int e1 = e0 + CHUNK; if (e1 > E) e1 = E;
    for (int e = e0 + tid; e < e1; e += 256) {
        int s = ei[e];
        int d = ei[E + e];
        int pos = atomicAdd(&lcur[d >> BUCK_BITS], 1);
        tmp[pos] = (s << BUCK_BITS) | (d & (BUCK_SZ - 1));
    }
}

// ---------- pass C: per-bucket degree + row_start + dinv + final CSR scatter ----------
// src_sorted stores BYTE offsets (src*64) for the fp16 row table.
__global__ __launch_bounds__(256) void binC_kernel(const int* __restrict__ counts,
                                                   const int* __restrict__ tmp,
                                                   int* __restrict__ src_sorted,
                                                   int* __restrict__ row_start,
                                                   float* __restrict__ dinv,
                                                   int N, int E, int B, int nbuck) {
    __shared__ int hist[BUCK_SZ];
    __shared__ int pre[BUCK_SZ];
    __shared__ int lcur[BUCK_SZ];
    int tid = threadIdx.x;
    int b = blockIdx.x;
    int base = b << BUCK_BITS;
    int e0 = counts[b * B];
    int e1 = (b + 1 < nbuck) ? counts[(b + 1) * B] : E;
    hist[tid] = 0;
    __syncthreads();
    for (int e = e0 + tid; e < e1; e += 256)
        atomicAdd(&hist[tmp[e] & (BUCK_SZ - 1)], 1);
    __syncthreads();
    int v = hist[tid];
    pre[tid] = v;
    __syncthreads();
    for (int off = 1; off < 256; off <<= 1) {
        int t = (tid >= off) ? pre[tid - off] : 0;
        __syncthreads();
        pre[tid] += t;
        __syncthreads();
    }
    int excl = pre[tid] - v;
    int node = base + tid;
    if (node < N) {
        row_start[node] = e0 + excl;
        dinv[node] = rsqrtf((float)v + 1.0f);     // +1 self-loop
        if (node == N - 1) row_start[N] = E;
    }
    lcur[tid] = e0 + excl;
    __syncthreads();
    for (int e = e0 + tid; e < e1; e += 256) {
        int p = tmp[e];
        int pos = atomicAdd(&lcur[p & (BUCK_SZ - 1)], 1);
        src_sorted[pos] = (p >> BUCK_BITS) << 6;   // byte offset of fp16 row
    }
}

// ---------- layer 1 dense: hs1 = fp16( dinv * (x @ W1) ) ----------
__global__ __launch_bounds__(256) void gemm1_kernel(const float* __restrict__ x,
                                                    const float* __restrict__ W,
                                                    const float* __restrict__ dinv,
                                                    __half* __restrict__ h, int N) {
    __shared__ float Ws[F_IN * H];
    __shared__ float xs[8 * F_IN];
    int tid = threadIdx.x;
    for (int i = tid; i < F_IN * H; i += 256) Ws[i] = W[i];
    int nb = blockIdx.x * 8;
    int navail = N - nb; if (navail > 8) navail = 8;
    const float* xb = x + (long long)nb * F_IN;
    for (int i = tid; i < navail * F_IN; i += 256) xs[i] = xb[i];
    __syncthreads();
    int nl = tid >> 5, f = tid & 31;
    int node = nb + nl;
    if (node < N) {
        float s = 0.f;
        #pragma unroll
        for (int k = 0; k < F_IN; k++) s += xs[nl * F_IN + k] * Ws[k * H + f];
        h[(long long)node * H + f] = __float2half(s * dinv[node]);
    }
}

// ---------- fused agg + GEMM (dwordx2 gathers: 4 edges per load instr) ----------
// Lane map per 32-lane node group: j4 = lane>>3 (edge sub-slot 0..3),
// fq = lane&7 (8B chunk = features 4fq..4fq+3). One dwordx2 load covers
// 4 edges per wave instruction; two loads per jb step = 8 edges.
// Invalid idx slots already hold the ZERO ROW offset (N*64) -> no guards.
__global__ __launch_bounds__(256) void agg_gemm_kernel(const int* __restrict__ row_start,
                                                       const int* __restrict__ src_sorted,
                                                       const float* __restrict__ dinv,
                                                       const __half* __restrict__ hs,
                                                       const float* __restrict__ b,
                                                       const float* __restrict__ Wn,
                                                       __half* __restrict__ hout, int N) {
    __shared__ float Ws[H * H];
    __shared__ float t[8 * H];
    int tid = threadIdx.x;
    for (int i = tid; i < H * H; i += 256) Ws[i] = Wn[i];
    int nl = tid >> 5;
    int lane32 = tid & 31;
    int j4 = lane32 >> 3;
    int fq = lane32 & 7;
    int node = blockIdx.x * 8 + nl;
    int zoff = N << 6;
    float2 a0 = make_float2(0.f, 0.f), a1 = make_float2(0.f, 0.f);
    if (node < N) {
        const char* hbase = (const char*)hs + (fq << 3);
        int e0 = row_start[node], e1 = row_start[node + 1];
        int idxv = (e0 + lane32 < e1) ? src_sorted[e0 + lane32] : zoff;
        for (int base = e0; base < e1; base += 32) {
            int w = e1 - base; if (w > 32) w = 32;
            int idxN = (base + 32 + lane32 < e1) ? src_sorted[base + 32 + lane32] : zoff;
            for (int jb = 0; jb < w; jb += 8) {
                int o0 = __shfl(idxv, jb + j4, 32);
                int o1 = __shfl(idxv, jb + 4 + j4, 32);
                uint2 g0 = *(const uint2*)(hbase + o0);
                uint2 g1 = *(const uint2*)(hbase + o1);
                float2 f00 = __half22float2(*(__half2*)&g0.x);
                float2 f01 = __half22float2(*(__half2*)&g0.y);
                float2 f10 = __half22float2(*(__half2*)&g1.x);
                float2 f11 = __half22float2(*(__half2*)&g1.y);
                a0.x += f00.x + f10.x; a0.y += f00.y + f10.y;
                a1.x += f01.x + f11.x; a1.y += f01.y + f11.y;
            }
            idxv = idxN;
        }
    }
    #pragma unroll
    for (int m = 8; m <= 16; m <<= 1) {
        a0.x += __shfl_xor(a0.x, m, 32);
        a0.y += __shfl_xor(a0.y, m, 32);
        a1.x += __shfl_xor(a1.x, m, 32);
        a1.y += __shfl_xor(a1.y, m, 32);
    }
    if (node < N && j4 == 0) {
        float di = dinv[node];
        uint2 sv = *(const uint2*)((const char*)hs + ((long long)node << 6) + (fq << 3));
        float2 s0 = __half22float2(*(__half2*)&sv.x);
        float2 s1 = __half22float2(*(__half2*)&sv.y);
        float4 bv = ((const float4*)b)[fq];
        float4 r;
        r.x = fmaxf(di * (a0.x + s0.x) + bv.x, 0.f);
        r.y = fmaxf(di * (a0.y + s0.y) + bv.y, 0.f);
        r.z = fmaxf(di * (a1.x + s1.x) + bv.z, 0.f);
        r.w = fmaxf(di * (a1.y + s1.y) + bv.w, 0.f);
        ((float4*)&t[nl * H])[fq] = r;
    }
    __syncthreads();
    if (node < N) {
        int f = lane32;
        float s = 0.f;
        #pragma unroll
        for (int k = 0; k < H; k++) s += t[nl * H + k] * Ws[k * H + f];
        hout[(long long)node * H + f] = __float2half(s * dinv[node]);
    }
}

// ---------- final layer: X5 = relu(...), pool into 64 spread copies ----------
__global__ __launch_bounds__(256) void agg_pool_kernel(const int* __restrict__ row_start,
                                                       const int* __restrict__ src_sorted,
                                                       const float* __restrict__ dinv,
                                                       const __half* __restrict__ hs,
                                                       const float* __restrict__ b,
                                                       float* __restrict__ gs, int N) {
    __shared__ float t[8 * H];
    int tid = threadIdx.x;
    int nl = tid >> 5;
    int lane32 = tid & 31;
    int j4 = lane32 >> 3;
    int fq = lane32 & 7;
    int node = blockIdx.x * 8 + nl;
    int zoff = N << 6;
    float2 a0 = make_float2(0.f, 0.f), a1 = make_float2(0.f, 0.f);
    if (node < N) {
        const char* hbase = (const char*)hs + (fq << 3);
        int e0 = row_start[node], e1 = row_start[node + 1];
        int idxv = (e0 + lane32 < e1) ? src_sorted[e0 + lane32] : zoff;
        for (int base = e0; base < e1; base += 32) {
            int w = e1 - base; if (w > 32) w = 32;
            int idxN = (base + 32 + lane32 < e1) ? src_sorted[base + 32 + lane32] : zoff;
            for (int jb = 0; jb < w; jb += 8) {
                int o0 = __shfl(idxv, jb + j4, 32);
                int o1 = __shfl(idxv, jb + 4 + j4, 32);
                uint2 g0 = *(const uint2*)(hbase + o0);
                uint2 g1 = *(const uint2*)(hbase + o1);
                float2 f00 = __half22float2(*(__half2*)&g0.x);
                float2 f01 = __half22float2(*(__half2*)&g0.y);
                float2 f10 = __half22float2(*(__half2*)&g1.x);
                float2 f11 = __half22float2(*(__half2*)&g1.y);
                a0.x += f00.x + f10.x; a0.y += f00.y + f10.y;
                a1.x += f01.x + f11.x; a1.y += f01.y + f11.y;
            }
            idxv = idxN;
        }
    }
    #pragma unroll
    for (int m = 8; m <= 16; m <<= 1) {
        a0.x += __shfl_xor(a0.x, m, 32);
        a0.y += __shfl_xor(a0.y, m, 32);
        a1.x += __shfl_xor(a1.x, m, 32);
        a1.y += __shfl_xor(a1.y, m, 32);
    }
    if (j4 == 0) {
        float4 r = make_float4(0.f, 0.f, 0.f, 0.f);
        if (node < N) {
            float di = dinv[node];
            uint2 sv = *(const uint2*)((const char*)hs + ((long long)node << 6) + (fq << 3));
            float2 s0 = __half22float2(*(__half2*)&sv.x);
            float2 s1 = __half22float2(*(__half2*)&sv.y);
            float4 bv = ((const float4*)b)[fq];
            r.x = fmaxf(di * (a0.x + s0.x) + bv.x, 0.f);
            r.y = fmaxf(di * (a0.y + s0.y) + bv.y, 0.f);
            r.z = fmaxf(di * (a1.x + s1.x) + bv.z, 0.f);
            r.w = fmaxf(di * (a1.y + s1.y) + bv.w, 0.f);
        }
        ((float4*)&t[nl * H])[fq] = r;
    }
    __syncthreads();
    if (tid < H) {
        float s = 0.f;
        #pragma unroll
        for (int rI = 0; rI < 8; rI++) s += t[rI * H + tid];
        atomicAdd(&gs[(blockIdx.x & 63) * H + tid], s);
    }
}

// ---------- head ----------
__global__ __launch_bounds__(64) void head_kernel(const float* __restrict__ gs,
                                                  const float* __restrict__ Wl1,
                                                  const float* __restrict__ bl1,
                                                  const float* __restrict__ Wl2,
                                                  const float* __restrict__ bl2,
                                                  float* __restrict__ out) {
    __shared__ float gg[H];
    __shared__ float t[16];
    int tid = threadIdx.x;
    if (tid < H) {
        float s = 0.f;
        for (int c = 0; c < 64; c++) s += gs[c * H + tid];
        gg[tid] = s;
    }
    __syncthreads();
    if (tid < 16) {
        float s = bl1[tid];
        #pragma unroll
        for (int k = 0; k < 32; k++) s += gg[k] * Wl1[k * 16 + tid];
        t[tid] = fmaxf(s, 0.f);
    }
    __syncthreads();
    if (tid < 3) {
        float s = bl2[tid];
        #pragma unroll
        for (int k = 0; k < 16; k++) s += t[k] * Wl2[k * 3 + tid];
        out[tid] = s;
    }
}

extern "C" void kernel_launch(void* const* d_in, const int* in_sizes, int n_in,
                              void* d_out, int out_size, void* d_ws, size_t ws_size,
                              hipStream_t stream) {
    const float* x   = (const float*)d_in[0];
    const int*   ei  = (const int*)d_in[1];
    const float* W1  = (const float*)d_in[2];
    const float* b1  = (const float*)d_in[3];
    const float* W2  = (const float*)d_in[4];
    const float* b2  = (const float*)d_in[5];
    const float* W3  = (const float*)d_in[6];
    const float* b3  = (const float*)d_in[7];
    const float* W4  = (const float*)d_in[8];
    const float* b4  = (const float*)d_in[9];
    const float* Wl1 = (const float*)d_in[10];
    const float* bl1 = (const float*)d_in[11];
    const float* Wl2 = (const float*)d_in[12];
    const float* bl2 = (const float*)d_in[13];
    float* out = (float*)d_out;

    const int N = in_sizes[0] / F_IN;
    const int E = in_sizes[1] / 2;
    const int nbuck = (N + BUCK_SZ - 1) >> BUCK_BITS;      // 586 for N=150000
    const int B = (E + CHUNK - 1) / CHUNK;                 // 147 for E=2.4M
    const int nC = nbuck * B;

    char* ws = (char*)d_ws;
    size_t off = 0;
    auto alloc = [&](size_t bytes) {
        char* p = ws + off;
        off += (bytes + 255) & ~(size_t)255;
        return p;
    };
    float* dinv       = (float*)alloc((size_t)N * 4);
    int*   row_start  = (int*)alloc((size_t)(N + 1) * 4);
    int*   counts     = (int*)alloc((size_t)nC * 4);
    int*   countsS    = (int*)alloc((size_t)nC * 4);
    int*   btot2      = (int*)alloc(((size_t)nC / 256 + 2) * 4);
    int*   src_sorted = (int*)alloc((size_t)E * 4);
    size_t bufBytes   = (size_t)(N + 1) * H * 2;           // fp16 rows + zero row
    size_t tmpBytes   = (size_t)E * 4;
    __half* bufA      = (__half*)alloc(bufBytes > tmpBytes ? bufBytes : tmpBytes);
    __half* bufB      = (__half*)alloc(bufBytes);
    float* gs         = (float*)alloc(64 * H * 4);
    int*   tmp        = (int*)bufA;    // pass-B scratch; dead after binC

    const int TB = 256;
    const int gC  = (nC + TB - 1) / TB;
    const int gN8 = (N + 7) / 8;

    // ---- CSR build (no global atomics anywhere) ----
    hipMemsetAsync(gs, 0, 64 * H * 4, stream);
    histA_kernel<<<B, TB, 0, stream>>>(ei, counts, E, B, nbuck);
    scan1_kernel<<<gC, TB, 0, stream>>>(counts, countsS, btot2, nC);
    scan2_kernel<<<1, 1024, 0, stream>>>(btot2, gC);
    scan3b_kernel<<<gC, TB, 0, stream>>>(countsS, btot2, counts, nC);
    binB_kernel<<<B, TB, 0, stream>>>(ei, counts, tmp, E, B, nbuck);
    binC_kernel<<<nbuck, TB, 0, stream>>>(counts, tmp, src_sorted, row_start, dinv,
                                          N, E, B, nbuck);
    // zero rows (index N) for the padded gathers; after binC (bufA aliased tmp)
    hipMemsetAsync(bufA + (size_t)N * H, 0, H * 2, stream);
    hipMemsetAsync(bufB + (size_t)N * H, 0, H * 2, stream);

    // ---- layers ----
    gemm1_kernel<<<gN8, TB, 0, stream>>>(x, W1, dinv, bufA, N);                                  // hs1
    agg_gemm_kernel<<<gN8, TB, 0, stream>>>(row_start, src_sorted, dinv, bufA, b1, W2, bufB, N); // hs2
    agg_gemm_kernel<<<gN8, TB, 0, stream>>>(row_start, src_sorted, dinv, bufB, b2, W3, bufA, N); // hs3
    agg_gemm_kernel<<<gN8, TB, 0, stream>>>(row_start, src_sorted, dinv, bufA, b3, W4, bufB, N); // hs4
    agg_pool_kernel<<<gN8, TB, 0, stream>>>(row_start, src_sorted, dinv, bufB, b4, gs, N);       // pool(X5)

    head_kernel<<<1, 64, 0, stream>>>(gs, Wl1, bl1, Wl2, bl2, out);
}

// Round 14
// 412.200 us; speedup vs baseline: 1.3013x; 1.0073x over previous
//
#include <hip/hip_runtime.h>
#include <hip/hip_fp16.h>

#define F_IN 61
#define H 32
#define BUCK_BITS 8                  // 256 nodes per bucket
#define BUCK_SZ   256
#define CHUNK     8192               // edges per block in hist/bin passes

// ---------- generic 3-level exclusive scan (for the counts array) ----------
__global__ __launch_bounds__(256) void scan1_kernel(const int* __restrict__ in,
                                                    int* __restrict__ scanned,
                                                    int* __restrict__ btot, int n) {
    __shared__ int s[256];
    int tid = threadIdx.x;
    int i = blockIdx.x * 256 + tid;
    int v = (i < n) ? in[i] : 0;
    s[tid] = v;
    __syncthreads();
    for (int off = 1; off < 256; off <<= 1) {
        int t = (tid >= off) ? s[tid - off] : 0;
        __syncthreads();
        s[tid] += t;
        __syncthreads();
    }
    if (i < n) scanned[i] = s[tid] - v;
    if (tid == 255) btot[blockIdx.x] = s[255];
}

__global__ __launch_bounds__(1024) void scan2_kernel(int* __restrict__ btot, int nB) {
    __shared__ int s[1024];
    int tid = threadIdx.x;
    int v = (tid < nB) ? btot[tid] : 0;
    s[tid] = v;
    __syncthreads();
    for (int off = 1; off < 1024; off <<= 1) {
        int t = (tid >= off) ? s[tid - off] : 0;
        __syncthreads();
        s[tid] += t;
        __syncthreads();
    }
    if (tid < nB) btot[tid] = s[tid] - v;
}

__global__ __launch_bounds__(256) void scan3b_kernel(const int* __restrict__ scanned,
                                                     const int* __restrict__ btot,
                                                     int* __restrict__ outv, int n) {
    int i = blockIdx.x * 256 + threadIdx.x;
    if (i < n) outv[i] = scanned[i] + btot[blockIdx.x];
}

// ---------- pass A: per-(block,bucket) histogram ----------
__global__ __launch_bounds__(256) void histA_kernel(const int* __restrict__ ei,
                                                    int* __restrict__ counts,
                                                    int E, int B, int nbuck) {
    __shared__ int h[640];
    int tid = threadIdx.x;
    for (int i = tid; i < nbuck; i += 256) h[i] = 0;
    __syncthreads();
    int e0 = blockIdx.x * CHUNK;
    int e1 = e0 + CHUNK; if (e1 > E) e1 = E;
    for (int e = e0 + tid; e < e1; e += 256)
        atomicAdd(&h[ei[E + e] >> BUCK_BITS], 1);
    __syncthreads();
    for (int i = tid; i < nbuck; i += 256) counts[i * B + blockIdx.x] = h[i];
}

// ---------- pass B: bin edges into per-(block,bucket) EXCLUSIVE ranges ----------
// pack = (src<<8)|(dst&255); src < 2^18 fits.
__global__ __launch_bounds__(256) void binB_kernel(const int* __restrict__ ei,
                                                   const int* __restrict__ counts,
                                                   int* __restrict__ tmp,
                                                   int E, int B, int nbuck) {
    __shared__ int lcur[640];
    int tid = threadIdx.x;
    for (int i = tid; i < nbuck; i += 256) lcur[i] = counts[i * B + blockIdx.x];
    __syncthreads();
    int e0 = blockIdx.x * CHUNK;
    int e1 = e0 + CHUNK; if (e1 > E) e1 = E;
    for (int e = e0 + tid; e < e1; e += 256) {
        int s = ei[e];
        int d = ei[E + e];
        int pos = atomicAdd(&lcur[d >> BUCK_BITS], 1);
        tmp[pos] = (s << BUCK_BITS) | (d & (BUCK_SZ - 1));
    }
}

// ---------- pass C: per-bucket degree + row_start + dinv + final CSR scatter ----------
// src_sorted stores BYTE offsets (src*32) for the u8 row table.
__global__ __launch_bounds__(256) void binC_kernel(const int* __restrict__ counts,
                                                   const int* __restrict__ tmp,
                                                   int* __restrict__ src_sorted,
                                                   int* __restrict__ row_start,
                                                   float* __restrict__ dinv,
                                                   int N, int E, int B, int nbuck) {
    __shared__ int hist[BUCK_SZ];
    __shared__ int pre[BUCK_SZ];
    __shared__ int lcur[BUCK_SZ];
    int tid = threadIdx.x;
    int b = blockIdx.x;
    int base = b << BUCK_BITS;
    int e0 = counts[b * B];
    int e1 = (b + 1 < nbuck) ? counts[(b + 1) * B] : E;
    hist[tid] = 0;
    __syncthreads();
    for (int e = e0 + tid; e < e1; e += 256)
        atomicAdd(&hist[tmp[e] & (BUCK_SZ - 1)], 1);
    __syncthreads();
    int v = hist[tid];
    pre[tid] = v;
    __syncthreads();
    for (int off = 1; off < 256; off <<= 1) {
        int t = (tid >= off) ? pre[tid - off] : 0;
        __syncthreads();
        pre[tid] += t;
        __syncthreads();
    }
    int excl = pre[tid] - v;
    int node = base + tid;
    if (node < N) {
        row_start[node] = e0 + excl;
        dinv[node] = rsqrtf((float)v + 1.0f);     // +1 self-loop
        if (node == N - 1) row_start[N] = E;
    }
    lcur[tid] = e0 + excl;
    __syncthreads();
    for (int e = e0 + tid; e < e1; e += 256) {
        int p = tmp[e];
        int pos = atomicAdd(&lcur[p & (BUCK_SZ - 1)], 1);
        src_sorted[pos] = (p >> BUCK_BITS) << 5;   // byte offset of u8 row
    }
}

// ---------- quantize helper: row absmax over 32 lanes, emit u8 + scale ----------
// v = (q - 128) * s_row, s_row = absmax/127.
__device__ __forceinline__ void quant_store(float v, int node, int lane32,
                                            unsigned char* __restrict__ hq,
                                            float* __restrict__ scales) {
    float a = fabsf(v);
    #pragma unroll
    for (int m = 1; m <= 16; m <<= 1) a = fmaxf(a, __shfl_xor(a, m, 32));
    float inv = (a > 0.f) ? 127.f / a : 0.f;
    int q = (int)rintf(v * inv) + 128;
    hq[((long long)node << 5) + lane32] = (unsigned char)q;
    if (lane32 == 0) scales[node] = a * (1.f / 127.f);
}

// ---------- layer 1 dense: hq1 = quant( dinv * (x @ W1) ) ----------
__global__ __launch_bounds__(256) void gemm1_kernel(const float* __restrict__ x,
                                                    const float* __restrict__ W,
                                                    const float* __restrict__ dinv,
                                                    unsigned char* __restrict__ hq,
                                                    float* __restrict__ scales, int N) {
    __shared__ float Ws[F_IN * H];
    __shared__ float xs[8 * F_IN];
    int tid = threadIdx.x;
    for (int i = tid; i < F_IN * H; i += 256) Ws[i] = W[i];
    int nb = blockIdx.x * 8;
    int navail = N - nb; if (navail > 8) navail = 8;
    const float* xb = x + (long long)nb * F_IN;
    for (int i = tid; i < navail * F_IN; i += 256) xs[i] = xb[i];
    __syncthreads();
    int nl = tid >> 5, f = tid & 31;
    int node = nb + nl;
    if (node < N) {
        float s = 0.f;
        #pragma unroll
        for (int k = 0; k < F_IN; k++) s += xs[nl * F_IN + k] * Ws[k * H + f];
        quant_store(s * dinv[node], node, f, hq, scales);
    }
}

// ---------- fused agg + GEMM (u8 rows, per-row scale; 32B rows, L2-resident) ----------
// Lane map per 32-lane node group: p = lane>>4 (edge parity), fp = lane&15
// (feature pair). Decode: v = (u-128)*s; sum = acc(u*s) - 128*accS.
// Invalid slots gather the ZERO ROW (bytes=128, scales[N]=0) -> contribute 0.
__global__ __launch_bounds__(256) void agg_gemm_kernel(const int* __restrict__ row_start,
                                                       const int* __restrict__ src_sorted,
                                                       const float* __restrict__ dinv,
                                                       const unsigned char* __restrict__ hq,
                                                       const float* __restrict__ scales,
                                                       const float* __restrict__ b,
                                                       const float* __restrict__ Wn,
                                                       unsigned char* __restrict__ hqout,
                                                       float* __restrict__ scalesout, int N) {
    __shared__ float Ws[H * H];
    __shared__ float t[8 * H];
    int tid = threadIdx.x;
    for (int i = tid; i < H * H; i += 256) Ws[i] = Wn[i];
    int nl = tid >> 5;
    int lane32 = tid & 31;
    int p = lane32 >> 4;
    int fp = lane32 & 15;
    int node = blockIdx.x * 8 + nl;
    int zoff = N << 5;
    float2 acc = make_float2(0.f, 0.f);
    float accS = 0.f;
    if (node < N) {
        const char* qbase = (const char*)hq + (fp << 1);
        const char* sbase = (const char*)scales;
        int e0 = row_start[node], e1 = row_start[node + 1];
        int idxv = (e0 + lane32 < e1) ? src_sorted[e0 + lane32] : zoff;
        for (int base = e0; base < e1; base += 32) {
            int w = e1 - base; if (w > 32) w = 32;
            int idxN = (base + 32 + lane32 < e1) ? src_sorted[base + 32 + lane32] : zoff;
            for (int j = 0; j < w; j += 16) {
                int offs[8];
                #pragma unroll
                for (int k = 0; k < 8; k++) offs[k] = __shfl(idxv, j + 2 * k + p, 32);
                unsigned short g[8];
                float sc[8];
                #pragma unroll
                for (int k = 0; k < 8; k++) {
                    g[k] = *(const unsigned short*)(qbase + offs[k]);
                    sc[k] = *(const float*)(sbase + (offs[k] >> 3));
                }
                #pragma unroll
                for (int k = 0; k < 8; k++) {
                    float u0 = (float)(unsigned char)(g[k]);
                    float u1 = (float)(unsigned char)(g[k] >> 8);
                    acc.x = fmaf(u0, sc[k], acc.x);
                    acc.y = fmaf(u1, sc[k], acc.y);
                    accS += sc[k];
                }
            }
            idxv = idxN;
        }
    }
    acc.x += __shfl_xor(acc.x, 16, 32);
    acc.y += __shfl_xor(acc.y, 16, 32);
    accS  += __shfl_xor(accS, 16, 32);
    if (node < N && p == 0) {
        float di = dinv[node];
        unsigned short gs_ = *(const unsigned short*)((const char*)hq +
                              ((long long)node << 5) + (fp << 1));
        float ssf = scales[node];
        float u0 = (float)(unsigned char)(gs_);
        float u1 = (float)(unsigned char)(gs_ >> 8);
        float T = accS + ssf;
        float vx = acc.x + u0 * ssf - 128.f * T;
        float vy = acc.y + u1 * ssf - 128.f * T;
        float2 bv = ((const float2*)b)[fp];
        float rx = fmaxf(di * vx + bv.x, 0.f);
        float ry = fmaxf(di * vy + bv.y, 0.f);
        ((float2*)&t[nl * H])[fp] = make_float2(rx, ry);
    }
    __syncthreads();
    if (node < N) {
        int f = lane32;
        float s = 0.f;
        #pragma unroll
        for (int k = 0; k < H; k++) s += t[nl * H + k] * Ws[k * H + f];
        quant_store(s * dinv[node], node, f, hqout, scalesout);
    }
}

// ---------- final layer: X5 = relu(...), pool into 64 spread copies ----------
__global__ __launch_bounds__(256) void agg_pool_kernel(const int* __restrict__ row_start,
                                                       const int* __restrict__ src_sorted,
                                                       const float* __restrict__ dinv,
                                                       const unsigned char* __restrict__ hq,
                                                       const float* __restrict__ scales,
                                                       const float* __restrict__ b,
                                                       float* __restrict__ gs, int N) {
    __shared__ float t[8 * H];
    int tid = threadIdx.x;
    int nl = tid >> 5;
    int lane32 = tid & 31;
    int p = lane32 >> 4;
    int fp = lane32 & 15;
    int node = blockIdx.x * 8 + nl;
    int zoff = N << 5;
    float2 acc = make_float2(0.f, 0.f);
    float accS = 0.f;
    if (node < N) {
        const char* qbase = (const char*)hq + (fp << 1);
        const char* sbase = (const char*)scales;
        int e0 = row_start[node], e1 = row_start[node + 1];
        int idxv = (e0 + lane32 < e1) ? src_sorted[e0 + lane32] : zoff;
        for (int base = e0; base < e1; base += 32) {
            int w = e1 - base; if (w > 32) w = 32;
            int idxN = (base + 32 + lane32 < e1) ? src_sorted[base + 32 + lane32] : zoff;
            for (int j = 0; j < w; j += 16) {
                int offs[8];
                #pragma unroll
                for (int k = 0; k < 8; k++) offs[k] = __shfl(idxv, j + 2 * k + p, 32);
                unsigned short g[8];
                float sc[8];
                #pragma unroll
                for (int k = 0; k < 8; k++) {
                    g[k] = *(const unsigned short*)(qbase + offs[k]);
                    sc[k] = *(const float*)(sbase + (offs[k] >> 3));
                }
                #pragma unroll
                for (int k = 0; k < 8; k++) {
                    float u0 = (float)(unsigned char)(g[k]);
                    float u1 = (float)(unsigned char)(g[k] >> 8);
                    acc.x = fmaf(u0, sc[k], acc.x);
                    acc.y = fmaf(u1, sc[k], acc.y);
                    accS += sc[k];
                }
            }
            idxv = idxN;
        }
    }
    acc.x += __shfl_xor(acc.x, 16, 32);
    acc.y += __shfl_xor(acc.y, 16, 32);
    accS  += __shfl_xor(accS, 16, 32);
    if (p == 0) {
        float2 r = make_float2(0.f, 0.f);
        if (node < N) {
            float di = dinv[node];
            unsigned short gs_ = *(const unsigned short*)((const char*)hq +
                                  ((long long)node << 5) + (fp << 1));
            float ssf = scales[node];
            float u0 = (float)(unsigned char)(gs_);
            float u1 = (float)(unsigned char)(gs_ >> 8);
            float T = accS + ssf;
            float vx = acc.x + u0 * ssf - 128.f * T;
            float vy = acc.y + u1 * ssf - 128.f * T;
            float2 bv = ((const float2*)b)[fp];
            r.x = fmaxf(di * vx + bv.x, 0.f);
            r.y = fmaxf(di * vy + bv.y, 0.f);
        }
        ((float2*)&t[nl * H])[fp] = r;
    }
    __syncthreads();
    if (tid < H) {
        float s = 0.f;
        #pragma unroll
        for (int rI = 0; rI < 8; rI++) s += t[rI * H + tid];
        atomicAdd(&gs[(blockIdx.x & 63) * H + tid], s);
    }
}

// ---------- head ----------
__global__ __launch_bounds__(64) void head_kernel(const float* __restrict__ gs,
                                                  const float* __restrict__ Wl1,
                                                  const float* __restrict__ bl1,
                                                  const float* __restrict__ Wl2,
                                                  const float* __restrict__ bl2,
                                                  float* __restrict__ out) {
    __shared__ float gg[H];
    __shared__ float t[16];
    int tid = threadIdx.x;
    if (tid < H) {
        float s = 0.f;
        for (int c = 0; c < 64; c++) s += gs[c * H + tid];
        gg[tid] = s;
    }
    __syncthreads();
    if (tid < 16) {
        float s = bl1[tid];
        #pragma unroll
        for (int k = 0; k < 32; k++) s += gg[k] * Wl1[k * 16 + tid];
        t[tid] = fmaxf(s, 0.f);
    }
    __syncthreads();
    if (tid < 3) {
        float s = bl2[tid];
        #pragma unroll
        for (int k = 0; k < 16; k++) s += t[k] * Wl2[k * 3 + tid];
        out[tid] = s;
    }
}

extern "C" void kernel_launch(void* const* d_in, const int* in_sizes, int n_in,
                              void* d_out, int out_size, void* d_ws, size_t ws_size,
                              hipStream_t stream) {
    const float* x   = (const float*)d_in[0];
    const int*   ei  = (const int*)d_in[1];
    const float* W1  = (const float*)d_in[2];
    const float* b1  = (const float*)d_in[3];
    const float* W2  = (const float*)d_in[4];
    const float* b2  = (const float*)d_in[5];
    const float* W3  = (const float*)d_in[6];
    const float* b3  = (const float*)d_in[7];
    const float* W4  = (const float*)d_in[8];
    const float* b4  = (const float*)d_in[9];
    const float* Wl1 = (const float*)d_in[10];
    const float* bl1 = (const float*)d_in[11];
    const float* Wl2 = (const float*)d_in[12];
    const float* bl2 = (const float*)d_in[13];
    float* out = (float*)d_out;

    const int N = in_sizes[0] / F_IN;
    const int E = in_sizes[1] / 2;
    const int nbuck = (N + BUCK_SZ - 1) >> BUCK_BITS;      // 586 for N=150000
    const int B = (E + CHUNK - 1) / CHUNK;                 // 293 for E=2.4M
    const int nC = nbuck * B;

    char* ws = (char*)d_ws;
    size_t off = 0;
    auto alloc = [&](size_t bytes) {
        char* p = ws + off;
        off += (bytes + 255) & ~(size_t)255;
        return p;
    };
    float* dinv       = (float*)alloc((size_t)N * 4);
    int*   row_start  = (int*)alloc((size_t)(N + 1) * 4);
    int*   counts     = (int*)alloc((size_t)nC * 4);
    int*   countsS    = (int*)alloc((size_t)nC * 4);
    int*   btot2      = (int*)alloc(((size_t)nC / 256 + 2) * 4);
    int*   src_sorted = (int*)alloc((size_t)E * 4);
    int*   tmp        = (int*)alloc((size_t)E * 4);
    unsigned char* hqA = (unsigned char*)alloc((size_t)(N + 1) * H);
    unsigned char* hqB = (unsigned char*)alloc((size_t)(N + 1) * H);
    float* scA        = (float*)alloc((size_t)(N + 1) * 4);
    float* scB        = (float*)alloc((size_t)(N + 1) * 4);
    float* gs         = (float*)alloc(64 * H * 4);

    const int TB = 256;
    const int gC  = (nC + TB - 1) / TB;
    const int gN8 = (N + 7) / 8;

    // ---- CSR build (no global atomics anywhere) ----
    hipMemsetAsync(gs, 0, 64 * H * 4, stream);
    // zero rows for padded gathers: bytes=128 (decodes to 0 with scale 0)
    hipMemsetAsync(hqA + (size_t)N * H, 128, H, stream);
    hipMemsetAsync(hqB + (size_t)N * H, 128, H, stream);
    hipMemsetAsync(scA + N, 0, 4, stream);
    hipMemsetAsync(scB + N, 0, 4, stream);
    histA_kernel<<<B, TB, 0, stream>>>(ei, counts, E, B, nbuck);
    scan1_kernel<<<gC, TB, 0, stream>>>(counts, countsS, btot2, nC);
    scan2_kernel<<<1, 1024, 0, stream>>>(btot2, gC);
    scan3b_kernel<<<gC, TB, 0, stream>>>(countsS, btot2, counts, nC);
    binB_kernel<<<B, TB, 0, stream>>>(ei, counts, tmp, E, B, nbuck);
    binC_kernel<<<nbuck, TB, 0, stream>>>(counts, tmp, src_sorted, row_start, dinv,
                                          N, E, B, nbuck);

    // ---- layers ----
    gemm1_kernel<<<gN8, TB, 0, stream>>>(x, W1, dinv, hqA, scA, N);
    agg_gemm_kernel<<<gN8, TB, 0, stream>>>(row_start, src_sorted, dinv, hqA, scA,
                                            b1, W2, hqB, scB, N);
    agg_gemm_kernel<<<gN8, TB, 0, stream>>>(row_start, src_sorted, dinv, hqB, scB,
                                            b2, W3, hqA, scA, N);
    agg_gemm_kernel<<<gN8, TB, 0, stream>>>(row_start, src_sorted, dinv, hqA, scA,
                                            b3, W4, hqB, scB, N);
    agg_pool_kernel<<<gN8, TB, 0, stream>>>(row_start, src_sorted, dinv, hqB, scB,
                                            b4, gs, N);

    head_kernel<<<1, 64, 0, stream>>>(gs, Wl1, bl1, Wl2, bl2, out);
}

// Round 15
// 379.083 us; speedup vs baseline: 1.4150x; 1.0874x over previous
//
#include <hip/hip_runtime.h>
#include <hip/hip_fp16.h>

#define F_IN 61
#define H 32
#define BUCK_BITS 8                  // 256 nodes per bucket
#define BUCK_SZ   256
#define CHUNK     8192               // edges per block in hist/bin passes

// ---------- scan level 1: per-256-block exclusive scan + block totals ----------
__global__ __launch_bounds__(256) void scan1_kernel(const int* __restrict__ in,
                                                    int* __restrict__ scanned,
                                                    int* __restrict__ btot, int n) {
    __shared__ int s[256];
    int tid = threadIdx.x;
    int i = blockIdx.x * 256 + tid;
    int v = (i < n) ? in[i] : 0;
    s[tid] = v;
    __syncthreads();
    for (int off = 1; off < 256; off <<= 1) {
        int t = (tid >= off) ? s[tid - off] : 0;
        __syncthreads();
        s[tid] += t;
        __syncthreads();
    }
    if (i < n) scanned[i] = s[tid] - v;
    if (tid == 255) btot[blockIdx.x] = s[255];
}

// ---------- scan level 2: exclusive scan of block totals (single block) ----------
__global__ __launch_bounds__(1024) void scan2_kernel(int* __restrict__ btot, int nB) {
    __shared__ int s[1024];
    int tid = threadIdx.x;
    int v = (tid < nB) ? btot[tid] : 0;
    s[tid] = v;
    __syncthreads();
    for (int off = 1; off < 1024; off <<= 1) {
        int t = (tid >= off) ? s[tid - off] : 0;
        __syncthreads();
        s[tid] += t;
        __syncthreads();
    }
    if (tid < nB) btot[tid] = s[tid] - v;
}

// ---------- pass A: per-(block,bucket) histogram; block 0 also zeroes gs ----------
__global__ __launch_bounds__(256) void histA_kernel(const int* __restrict__ ei,
                                                    int* __restrict__ counts,
                                                    float* __restrict__ gs,
                                                    int E, int B, int nbuck) {
    __shared__ int h[640];
    int tid = threadIdx.x;
    if (blockIdx.x == 0) {
        #pragma unroll
        for (int r = 0; r < 8; r++) gs[r * 256 + tid] = 0.f;   // 64*H floats
    }
    for (int i = tid; i < nbuck; i += 256) h[i] = 0;
    __syncthreads();
    int e0 = blockIdx.x * CHUNK;
    int e1 = e0 + CHUNK; if (e1 > E) e1 = E;
    for (int e = e0 + tid; e < e1; e += 256)
        atomicAdd(&h[ei[E + e] >> BUCK_BITS], 1);
    __syncthreads();
    for (int i = tid; i < nbuck; i += 256) counts[i * B + blockIdx.x] = h[i];
}

// ---------- pass B: bin edges into per-(block,bucket) EXCLUSIVE ranges ----------
// Reads scan results directly (scan3 folded): excl[i] = countsS[i] + btot[i>>8].
// pack = (src<<8)|(dst&255); src < 2^18 fits.
__global__ __launch_bounds__(256) void binB_kernel(const int* __restrict__ ei,
                                                   const int* __restrict__ countsS,
                                                   const int* __restrict__ btot,
                                                   int* __restrict__ tmp,
                                                   int E, int B, int nbuck) {
    __shared__ int lcur[640];
    int tid = threadIdx.x;
    for (int i = tid; i < nbuck; i += 256) {
        int ci = i * B + blockIdx.x;
        lcur[i] = countsS[ci] + btot[ci >> 8];
    }
    __syncthreads();
    int e0 = blockIdx.x * CHUNK;
    int e1 = e0 + CHUNK; if (e1 > E) e1 = E;
    for (int e = e0 + tid; e < e1; e += 256) {
        int s = ei[e];
        int d = ei[E + e];
        int pos = atomicAdd(&lcur[d >> BUCK_BITS], 1);
        tmp[pos] = (s << BUCK_BITS) | (d & (BUCK_SZ - 1));
    }
}

// ---------- pass C: per-bucket degree + row_start + dinv + final CSR scatter ----------
// src_sorted stores BYTE offsets (src*64) for the fp16 row table.
// Block 0 also writes the zero rows (index N) of both fp16 buffers.
__global__ __launch_bounds__(256) void binC_kernel(const int* __restrict__ countsS,
                                                   const int* __restrict__ btot,
                                                   const int* __restrict__ tmp,
                                                   int* __restrict__ src_sorted,
                                                   int* __restrict__ row_start,
                                                   float* __restrict__ dinv,
                                                   __half* __restrict__ bufA,
                                                   __half* __restrict__ bufB,
                                                   int N, int E, int B, int nbuck) {
    __shared__ int hist[BUCK_SZ];
    __shared__ int pre[BUCK_SZ];
    __shared__ int lcur[BUCK_SZ];
    int tid = threadIdx.x;
    int b = blockIdx.x;
    int base = b << BUCK_BITS;
    if (b == 0 && tid < H) {                 // zero rows for padded gathers
        bufA[(size_t)N * H + tid] = __float2half(0.f);
        bufB[(size_t)N * H + tid] = __float2half(0.f);
    }
    int c0 = b * B;
    int e0 = countsS[c0] + btot[c0 >> 8];
    int e1 = E;
    if (b + 1 < nbuck) {
        int c1 = (b + 1) * B;
        e1 = countsS[c1] + btot[c1 >> 8];
    }
    hist[tid] = 0;
    __syncthreads();
    for (int e = e0 + tid; e < e1; e += 256)
        atomicAdd(&hist[tmp[e] & (BUCK_SZ - 1)], 1);
    __syncthreads();
    int v = hist[tid];
    pre[tid] = v;
    __syncthreads();
    for (int off = 1; off < 256; off <<= 1) {
        int t = (tid >= off) ? pre[tid - off] : 0;
        __syncthreads();
        pre[tid] += t;
        __syncthreads();
    }
    int excl = pre[tid] - v;
    int node = base + tid;
    if (node < N) {
        row_start[node] = e0 + excl;
        dinv[node] = rsqrtf((float)v + 1.0f);     // +1 self-loop
        if (node == N - 1) row_start[N] = E;
    }
    lcur[tid] = e0 + excl;
    __syncthreads();
    for (int e = e0 + tid; e < e1; e += 256) {
        int p = tmp[e];
        int pos = atomicAdd(&lcur[p & (BUCK_SZ - 1)], 1);
        src_sorted[pos] = (p >> BUCK_BITS) << 6;   // byte offset of fp16 row
    }
}

// ---------- layer 1 dense: hs1 = fp16( dinv * (x @ W1) ) ----------
__global__ __launch_bounds__(256) void gemm1_kernel(const float* __restrict__ x,
                                                    const float* __restrict__ W,
                                                    const float* __restrict__ dinv,
                                                    __half* __restrict__ h, int N) {
    __shared__ float Ws[F_IN * H];
    __shared__ float xs[8 * F_IN];
    int tid = threadIdx.x;
    for (int i = tid; i < F_IN * H; i += 256) Ws[i] = W[i];
    int nb = blockIdx.x * 8;
    int navail = N - nb; if (navail > 8) navail = 8;
    const float* xb = x + (long long)nb * F_IN;
    for (int i = tid; i < navail * F_IN; i += 256) xs[i] = xb[i];
    __syncthreads();
    int nl = tid >> 5, f = tid & 31;
    int node = nb + nl;
    if (node < N) {
        float s = 0.f;
        #pragma unroll
        for (int k = 0; k < F_IN; k++) s += xs[nl * F_IN + k] * Ws[k * H + f];
        h[(long long)node * H + f] = __float2half(s * dinv[node]);
    }
}

// ---------- fused agg + GEMM (half2 gathers, v_pk_add_f16 accumulate) ----------
// Lane map per node (32 lanes): p = lane>>4 (edge parity), fp = lane&15
// (feature pair). 8 independent gathers in flight; accumulate with packed
// fp16 adds (1 instr / 2 features) into two interleaved accumulators.
// Invalid slots gather the ZERO ROW at byte offset N*64.
__global__ __launch_bounds__(256) void agg_gemm_kernel(const int* __restrict__ row_start,
                                                       const int* __restrict__ src_sorted,
                                                       const float* __restrict__ dinv,
                                                       const __half* __restrict__ hs,
                                                       const float* __restrict__ b,
                                                       const float* __restrict__ Wn,
                                                       __half* __restrict__ hout, int N) {
    __shared__ float Ws[H * H];
    __shared__ float t[8 * H];
    int tid = threadIdx.x;
    for (int i = tid; i < H * H; i += 256) Ws[i] = Wn[i];
    int nl = tid >> 5;
    int lane32 = tid & 31;
    int p = lane32 >> 4;
    int fp = lane32 & 15;
    int node = blockIdx.x * 8 + nl;
    int zoff = N << 6;
    __half2 accA = __floats2half2_rn(0.f, 0.f);
    __half2 accB = __floats2half2_rn(0.f, 0.f);
    if (node < N) {
        const char* hbase = (const char*)hs + (fp << 2);
        int e0 = row_start[node], e1 = row_start[node + 1];
        int idxv = (e0 + lane32 < e1) ? src_sorted[e0 + lane32] : zoff;
        for (int base = e0; base < e1; base += 32) {
            int w = e1 - base; if (w > 32) w = 32;
            int idxN = (base + 32 + lane32 < e1) ? src_sorted[base + 32 + lane32] : zoff;
            for (int j = 0; j < w; j += 16) {
                int offs[8];
                #pragma unroll
                for (int k = 0; k < 8; k++) offs[k] = __shfl(idxv, j + 2 * k + p, 32);
                unsigned g[8];
                #pragma unroll
                for (int k = 0; k < 8; k++) g[k] = *(const unsigned*)(hbase + offs[k]);
                #pragma unroll
                for (int k = 0; k < 8; k += 2) {
                    accA = __hadd2(accA, *(__half2*)&g[k]);
                    accB = __hadd2(accB, *(__half2*)&g[k + 1]);
                }
            }
            idxv = idxN;
        }
    }
    __half2 accH = __hadd2(accA, accB);
    float2 acc = __half22float2(accH);
    acc.x += __shfl_xor(acc.x, 16, 32);
    acc.y += __shfl_xor(acc.y, 16, 32);
    if (node < N && p == 0) {
        float di = dinv[node];
        unsigned sv = *(const unsigned*)((const char*)hs + ((long long)node << 6) + (fp << 2));
        float2 s2 = __half22float2(*(__half2*)&sv);
        float2 bv = ((const float2*)b)[fp];
        float rx = fmaxf(di * (acc.x + s2.x) + bv.x, 0.f);
        float ry = fmaxf(di * (acc.y + s2.y) + bv.y, 0.f);
        ((float2*)&t[nl * H])[fp] = make_float2(rx, ry);
    }
    __syncthreads();
    if (node < N) {
        int f = lane32;
        float s = 0.f;
        #pragma unroll
        for (int k = 0; k < H; k++) s += t[nl * H + k] * Ws[k * H + f];
        hout[(long long)node * H + f] = __float2half(s * dinv[node]);
    }
}

// ---------- final layer: X5 = relu(...), pool into 64 spread copies ----------
__global__ __launch_bounds__(256) void agg_pool_kernel(const int* __restrict__ row_start,
                                                       const int* __restrict__ src_sorted,
                                                       const float* __restrict__ dinv,
                                                       const __half* __restrict__ hs,
                                                       const float* __restrict__ b,
                                                       float* __restrict__ gs, int N) {
    __shared__ float t[8 * H];
    int tid = threadIdx.x;
    int nl = tid >> 5;
    int lane32 = tid & 31;
    int p = lane32 >> 4;
    int fp = lane32 & 15;
    int node = blockIdx.x * 8 + nl;
    int zoff = N << 6;
    __half2 accA = __floats2half2_rn(0.f, 0.f);
    __half2 accB = __floats2half2_rn(0.f, 0.f);
    if (node < N) {
        const char* hbase = (const char*)hs + (fp << 2);
        int e0 = row_start[node], e1 = row_start[node + 1];
        int idxv = (e0 + lane32 < e1) ? src_sorted[e0 + lane32] : zoff;
        for (int base = e0; base < e1; base += 32) {
            int w = e1 - base; if (w > 32) w = 32;
            int idxN = (base + 32 + lane32 < e1) ? src_sorted[base + 32 + lane32] : zoff;
            for (int j = 0; j < w; j += 16) {
                int offs[8];
                #pragma unroll
                for (int k = 0; k < 8; k++) offs[k] = __shfl(idxv, j + 2 * k + p, 32);
                unsigned g[8];
                #pragma unroll
                for (int k = 0; k < 8; k++) g[k] = *(const unsigned*)(hbase + offs[k]);
                #pragma unroll
                for (int k = 0; k < 8; k += 2) {
                    accA = __hadd2(accA, *(__half2*)&g[k]);
                    accB = __hadd2(accB, *(__half2*)&g[k + 1]);
                }
            }
            idxv = idxN;
        }
    }
    __half2 accH = __hadd2(accA, accB);
    float2 acc = __half22float2(accH);
    acc.x += __shfl_xor(acc.x, 16, 32);
    acc.y += __shfl_xor(acc.y, 16, 32);
    if (p == 0) {
        float2 r = make_float2(0.f, 0.f);
        if (node < N) {
            float di = dinv[node];
            unsigned sv = *(const unsigned*)((const char*)hs + ((long long)node << 6) + (fp << 2));
            float2 s2 = __half22float2(*(__half2*)&sv);
            float2 bv = ((const float2*)b)[fp];
            r.x = fmaxf(di * (acc.x + s2.x) + bv.x, 0.f);
            r.y = fmaxf(di * (acc.y + s2.y) + bv.y, 0.f);
        }
        ((float2*)&t[nl * H])[fp] = r;
    }
    __syncthreads();
    if (tid < H) {
        float s = 0.f;
        #pragma unroll
        for (int rI = 0; rI < 8; rI++) s += t[rI * H + tid];
        atomicAdd(&gs[(blockIdx.x & 63) * H + tid], s);
    }
}

// ---------- head ----------
__global__ __launch_bounds__(64) void head_kernel(const float* __restrict__ gs,
                                                  const float* __restrict__ Wl1,
                                                  const float* __restrict__ bl1,
                                                  const float* __restrict__ Wl2,
                                                  const float* __restrict__ bl2,
                                                  float* __restrict__ out) {
    __shared__ float gg[H];
    __shared__ float t[16];
    int tid = threadIdx.x;
    if (tid < H) {
        float s = 0.f;
        for (int c = 0; c < 64; c++) s += gs[c * H + tid];
        gg[tid] = s;
    }
    __syncthreads();
    if (tid < 16) {
        float s = bl1[tid];
        #pragma unroll
        for (int k = 0; k < 32; k++) s += gg[k] * Wl1[k * 16 + tid];
        t[tid] = fmaxf(s, 0.f);
    }
    __syncthreads();
    if (tid < 3) {
        float s = bl2[tid];
        #pragma unroll
        for (int k = 0; k < 16; k++) s += t[k] * Wl2[k * 3 + tid];
        out[tid] = s;
    }
}

extern "C" void kernel_launch(void* const* d_in, const int* in_sizes, int n_in,
                              void* d_out, int out_size, void* d_ws, size_t ws_size,
                              hipStream_t stream) {
    const float* x   = (const float*)d_in[0];
    const int*   ei  = (const int*)d_in[1];
    const float* W1  = (const float*)d_in[2];
    const float* b1  = (const float*)d_in[3];
    const float* W2  = (const float*)d_in[4];
    const float* b2  = (const float*)d_in[5];
    const float* W3  = (const float*)d_in[6];
    const float* b3  = (const float*)d_in[7];
    const float* W4  = (const float*)d_in[8];
    const float* b4  = (const float*)d_in[9];
    const float* Wl1 = (const float*)d_in[10];
    const float* bl1 = (const float*)d_in[11];
    const float* Wl2 = (const float*)d_in[12];
    const float* bl2 = (const float*)d_in[13];
    float* out = (float*)d_out;

    const int N = in_sizes[0] / F_IN;
    const int E = in_sizes[1] / 2;
    const int nbuck = (N + BUCK_SZ - 1) >> BUCK_BITS;      // 586 for N=150000
    const int B = (E + CHUNK - 1) / CHUNK;                 // 293 for E=2.4M
    const int nC = nbuck * B;

    char* ws = (char*)d_ws;
    size_t off = 0;
    auto alloc = [&](size_t bytes) {
        char* p = ws + off;
        off += (bytes + 255) & ~(size_t)255;
        return p;
    };
    float* dinv       = (float*)alloc((size_t)N * 4);
    int*   row_start  = (int*)alloc((size_t)(N + 1) * 4);
    int*   counts     = (int*)alloc((size_t)nC * 4);
    int*   countsS    = (int*)alloc((size_t)nC * 4);
    int*   btot2      = (int*)alloc(((size_t)nC / 256 + 2) * 4);
    int*   src_sorted = (int*)alloc((size_t)E * 4);
    int*   tmp        = (int*)alloc((size_t)E * 4);
    __half* bufA      = (__half*)alloc((size_t)(N + 1) * H * 2);   // fp16 rows + zero row
    __half* bufB      = (__half*)alloc((size_t)(N + 1) * H * 2);
    float* gs         = (float*)alloc(64 * H * 4);

    const int TB = 256;
    const int gC  = (nC + TB - 1) / TB;   // 675 blocks <= 1024 for scan2
    const int gN8 = (N + 7) / 8;

    // ---- CSR build (no global atomics, no memsets — all folded) ----
    histA_kernel<<<B, TB, 0, stream>>>(ei, counts, gs, E, B, nbuck);
    scan1_kernel<<<gC, TB, 0, stream>>>(counts, countsS, btot2, nC);
    scan2_kernel<<<1, 1024, 0, stream>>>(btot2, gC);
    binB_kernel<<<B, TB, 0, stream>>>(ei, countsS, btot2, tmp, E, B, nbuck);
    binC_kernel<<<nbuck, TB, 0, stream>>>(countsS, btot2, tmp, src_sorted, row_start,
                                          dinv, bufA, bufB, N, E, B, nbuck);

    // ---- layers ----
    gemm1_kernel<<<gN8, TB, 0, stream>>>(x, W1, dinv, bufA, N);                                  // hs1
    agg_gemm_kernel<<<gN8, TB, 0, stream>>>(row_start, src_sorted, dinv, bufA, b1, W2, bufB, N); // hs2
    agg_gemm_kernel<<<gN8, TB, 0, stream>>>(row_start, src_sorted, dinv, bufB, b2, W3, bufA, N); // hs3
    agg_gemm_kernel<<<gN8, TB, 0, stream>>>(row_start, src_sorted, dinv, bufA, b3, W4, bufB, N); // hs4
    agg_pool_kernel<<<gN8, TB, 0, stream>>>(row_start, src_sorted, dinv, bufB, b4, gs, N);       // pool(X5)

    head_kernel<<<1, 64, 0, stream>>>(gs, Wl1, bl1, Wl2, bl2, out);
}